// Round 4
// baseline (226.840 us; speedup 1.0000x reference)
//
#include <hip/hip_runtime.h>

// Cosine-sim attention, B=4 H=8 d=128 T=2048, alpha=5.
// R4: V prepass eliminated (attn stages V fp32->bf16 via VGPR into the
// double-buffered frag-linear LDS); K prepass rewritten register-resident
// (coalesced loads, bf16-only LDS transpose, 17 KB LDS). Attn structure
// (1-barrier dbuf pipeline, bounded softmax, fused Q-norm) frozen from R3.

#define T_SEQ 2048
#define DH 128
#define BH 32   // B*H

typedef float f32x4 __attribute__((ext_vector_type(4)));
typedef __bf16 bf16x8 __attribute__((ext_vector_type(8)));
typedef __bf16 bf16x4 __attribute__((ext_vector_type(4)));

__device__ __forceinline__ void async_copy16(const void* g, void* l) {
  __builtin_amdgcn_global_load_lds(
      (const __attribute__((address_space(1))) void*)g,
      (__attribute__((address_space(3))) void*)l, 16, 0, 0);
}

// ---------- K prepass: L2-normalize over ch, transpose, bf16 ----------
// ksrc: [bh][128][T] fp32 -> kn: [bh][T][128] bf16 unit-norm.
// Thread (wave=seg -> ch block, lane=t): 32 coalesced dword loads (256 B/instr),
// register-resident; transpose via bf16 LDS only.
__global__ __launch_bounds__(256) void prepass_k_kernel(
    const float* __restrict__ ksrc, __bf16* __restrict__ kn) {
  __shared__ float part[4][64];
  __shared__ float inv_s[64];
  __shared__ __bf16 tile[64 * 136];   // [t][ch] stride 136
  const int bh = blockIdx.x >> 5;
  const int t0 = (blockIdx.x & 31) * 64;
  const int tid = threadIdx.x;
  const int seg = tid >> 6;           // wave id -> ch chunk of 32
  const int t = tid & 63;

  const float* src = ksrc + (size_t)bh * DH * T_SEQ + t0 + t;
  float x[32];
  float ss = 0.f;
#pragma unroll
  for (int i = 0; i < 32; ++i) {
    x[i] = src[(size_t)(seg * 32 + i) * T_SEQ];
    ss += x[i] * x[i];
  }
  part[seg][t] = ss;
  __syncthreads();
  if (tid < 64) {
    float n = sqrtf(part[0][tid] + part[1][tid] + part[2][tid] + part[3][tid]);
    inv_s[tid] = 1.f / fmaxf(n, 1e-12f);
  }
  __syncthreads();
  const float inv = inv_s[t];
#pragma unroll
  for (int o = 0; o < 4; ++o) {
    bf16x8 ob;
#pragma unroll
    for (int j = 0; j < 8; ++j) ob[j] = (__bf16)(x[o * 8 + j] * inv);
    *(bf16x8*)(tile + t * 136 + seg * 32 + o * 8) = ob;
  }
  __syncthreads();
  const int t2 = tid >> 2;
  const int c0 = (tid & 3) * 32;
  __bf16* drow = kn + (size_t)(bh * T_SEQ + t0 + t2) * DH + c0;
#pragma unroll
  for (int cc = 0; cc < 4; ++cc)
    *(bf16x8*)(drow + cc * 8) = *(const bf16x8*)(tile + t2 * 136 + c0 + cc * 8);
}

// ---------- flash attention ----------
// q: [bh][128][T] fp32 (normalized in-kernel, alpha folded)
// kn: [bh][T][128] bf16 unit-norm ; v: [bh][128][T] fp32 (staged in-kernel)
// out: [bh][128][T] fp32
__device__ __forceinline__ void stage_k(
    const __bf16* kbase, __bf16* lk, int koff, int w, int qi, int g) {
#pragma unroll
  for (int i = 0; i < 4; ++i) {
    const int f = w * 4 + i;          // frag: mt = f>>2, s = f&3
    const int mt = f >> 2, s = f & 3;
    async_copy16(kbase + (size_t)(koff + mt * 16 + qi) * DH + s * 32 + g * 8,
                 lk + f * 512);
  }
}

__device__ __forceinline__ void stage_v_loads(
    const float* vsrc, int k0, int tid, f32x4* x) {
#pragma unroll
  for (int i = 0; i < 8; ++i) {
    const int c = i * 256 + tid;
    const int ch = c >> 4, t4 = (c & 15) * 4;
    x[i] = *(const f32x4*)(vsrc + (size_t)ch * T_SEQ + k0 + t4);
  }
}

// write x into frag-linear lds_v: A[m=ch][k=key] with m=mt*16+qi', k=st*32+g'*8+j
__device__ __forceinline__ void stage_v_write(
    __bf16* lv, int tid, const f32x4* x) {
#pragma unroll
  for (int i = 0; i < 8; ++i) {
    const int c = i * 256 + tid;
    const int ch = c >> 4, t4 = (c & 15) * 4;
    const int f = ((ch >> 4) << 1) + (t4 >> 5);
    const int idx = f * 512 + ((((t4 & 31) >> 3) * 16 + (ch & 15)) << 3) + (t4 & 7);
    bf16x4 ob;
    ob[0] = (__bf16)x[i][0]; ob[1] = (__bf16)x[i][1];
    ob[2] = (__bf16)x[i][2]; ob[3] = (__bf16)x[i][3];
    *(bf16x4*)(lv + idx) = ob;
  }
}

__global__ __launch_bounds__(256, 2) void attn_kernel(
    const float* __restrict__ q, const __bf16* __restrict__ kn,
    const float* __restrict__ v, float* __restrict__ out) {
  __shared__ __align__(16) __bf16 lds_k[2][16 * 512];   // 32 KB
  __shared__ __align__(16) __bf16 lds_v[2][16 * 512];   // 32 KB
  __shared__ __align__(16) __bf16 p_buf[8 * 1024];      // 16 KB, XOR-swizzled
  // total 81920 B -> 2 blocks/CU

  const int bh = blockIdx.x >> 4;
  const int q0 = (blockIdx.x & 15) * 128;
  const int tid = threadIdx.x;
  const int w = tid >> 6, lane = tid & 63;
  const int qi = lane & 15, g = lane >> 4;

  const __bf16* kbase = kn + (size_t)bh * (T_SEQ * DH);
  const float* vsrc = v + (size_t)bh * (DH * T_SEQ);
  const float* qsrc = q + (size_t)bh * (DH * T_SEQ);

  f32x4 vx[8];
  stage_k(kbase, lds_k[0], 0, w, qi, g);
  stage_v_loads(vsrc, 0, tid, vx);

  // fused Q normalize (alpha folded): qf = B[n=q][k=ch] frags (overlaps loads)
  bf16x8 qf[2][4];
#pragma unroll
  for (int nt = 0; nt < 2; ++nt) {
    const int t = q0 + w * 32 + nt * 16 + qi;
    float xv[32];
    float ss = 0.f;
#pragma unroll
    for (int s = 0; s < 4; ++s)
#pragma unroll
      for (int j = 0; j < 8; ++j) {
        float xq = qsrc[(size_t)(s * 32 + g * 8 + j) * T_SEQ + t];
        xv[s * 8 + j] = xq;
        ss += xq * xq;
      }
    ss += __shfl_xor(ss, 16, 64);
    ss += __shfl_xor(ss, 32, 64);
    const float inv = 5.0f / fmaxf(sqrtf(ss), 1e-12f);
#pragma unroll
    for (int s = 0; s < 4; ++s) {
      bf16x8 f;
#pragma unroll
      for (int j = 0; j < 8; ++j) f[j] = (__bf16)(xv[s * 8 + j] * inv);
      qf[nt][s] = f;
    }
  }
  stage_v_write(lds_v[0], tid, vx);

  f32x4 o_acc[2][8];
#pragma unroll
  for (int nt = 0; nt < 2; ++nt)
#pragma unroll
    for (int i = 0; i < 8; ++i) o_acc[nt][i] = (f32x4)(0.f);
  float lsum[2] = {0.f, 0.f};

  const int swz = (qi & 7) << 3;
  __bf16* pw0 = p_buf + (w * 2 + 0) * 1024 + qi * 64;
  __bf16* pw1 = p_buf + (w * 2 + 1) * 1024 + qi * 64;

  for (int it = 0; it < 32; ++it) {
    __syncthreads();   // drains K-DMA + V ds_writes issued last iter
    const int cur = it & 1;
    const bool pf = (it + 1 < 32);
    if (pf) {
      stage_k(kbase, lds_k[cur ^ 1], (it + 1) * 64, w, qi, g);
      stage_v_loads(vsrc, (it + 1) * 64, tid, vx);
    }

    // ---- S^T = K . Q (A-frag shared across both n-tiles) ----
    const __bf16* lk = lds_k[cur];
    f32x4 sacc[2][4];
#pragma unroll
    for (int nt = 0; nt < 2; ++nt)
#pragma unroll
      for (int mt = 0; mt < 4; ++mt) sacc[nt][mt] = (f32x4)(0.f);
#pragma unroll
    for (int s = 0; s < 4; ++s)
#pragma unroll
      for (int mt = 0; mt < 4; ++mt) {
        bf16x8 a = *(const bf16x8*)(lk + ((mt * 4 + s) * 64 + lane) * 8);
        sacc[0][mt] = __builtin_amdgcn_mfma_f32_16x16x32_bf16(a, qf[0][s], sacc[0][mt], 0, 0, 0);
        sacc[1][mt] = __builtin_amdgcn_mfma_f32_16x16x32_bf16(a, qf[1][s], sacc[1][mt], 0, 0, 0);
      }

    // ---- bounded softmax: p = exp(s), s in [-5,5]; no max tracking ----
#pragma unroll
    for (int nt = 0; nt < 2; ++nt) {
      __bf16* pw = nt ? pw1 : pw0;
      float rs = 0.f;
#pragma unroll
      for (int mt = 0; mt < 4; ++mt) {
        bf16x4 pb;
#pragma unroll
        for (int r = 0; r < 4; ++r) {
          float e = __expf(sacc[nt][mt][r]);
          rs += e;
          pb[r] = (__bf16)e;
        }
        *(bf16x4*)(pw + ((mt * 16 + g * 4) ^ swz)) = pb;
      }
      lsum[nt] += rs;
    }

    // ---- O^T += V . P^T ----
    const __bf16* lv = lds_v[cur];
#pragma unroll
    for (int st = 0; st < 2; ++st) {
      bf16x8 pf0 = *(const bf16x8*)(pw0 + ((st * 32 + g * 8) ^ swz));
      bf16x8 pf1 = *(const bf16x8*)(pw1 + ((st * 32 + g * 8) ^ swz));
#pragma unroll
      for (int mt = 0; mt < 8; ++mt) {
        bf16x8 a = *(const bf16x8*)(lv + ((mt * 2 + st) * 64 + lane) * 8);
        o_acc[0][mt] = __builtin_amdgcn_mfma_f32_16x16x32_bf16(a, pf0, o_acc[0][mt], 0, 0, 0);
        o_acc[1][mt] = __builtin_amdgcn_mfma_f32_16x16x32_bf16(a, pf1, o_acc[1][mt], 0, 0, 0);
      }
    }

    // ---- V(it+1) cvt + LDS write into inactive buffer (max vmcnt slack) ----
    if (pf) stage_v_write(lds_v[cur ^ 1], tid, vx);
  }

  // ---- epilogue ----
#pragma unroll
  for (int nt = 0; nt < 2; ++nt) {
    float l = lsum[nt];
    l += __shfl_xor(l, 16, 64);
    l += __shfl_xor(l, 32, 64);
    const float rinv = 1.f / l;
    const int tq = q0 + w * 32 + nt * 16 + qi;
#pragma unroll
    for (int mt = 0; mt < 8; ++mt)
#pragma unroll
      for (int r = 0; r < 4; ++r)
        out[(size_t)(bh * DH + mt * 16 + g * 4 + r) * T_SEQ + tq] =
            o_acc[nt][mt][r] * rinv;
  }
}

extern "C" void kernel_launch(void* const* d_in, const int* in_sizes, int n_in,
                              void* d_out, int out_size, void* d_ws, size_t ws_size,
                              hipStream_t stream) {
  const float* q = (const float*)d_in[0];
  const float* k = (const float*)d_in[1];
  const float* v = (const float*)d_in[2];
  float* out = (float*)d_out;
  const size_t n = (size_t)BH * T_SEQ * DH;
  if (ws_size < n * sizeof(__bf16)) return;
  __bf16* kn = (__bf16*)d_ws;

  prepass_k_kernel<<<dim3(1024), dim3(256), 0, stream>>>(k, kn);
  attn_kernel<<<dim3(512), dim3(256), 0, stream>>>(q, kn, v, out);
}

// Round 5
// 211.406 us; speedup vs baseline: 1.0730x; 1.0730x over previous
//
#include <hip/hip_runtime.h>

// Cosine-sim attention, B=4 H=8 d=128 T=2048, alpha=5.
// R5: attn reverted to R3 structure (1-barrier dbuf, DMA-staged K+V bf16,
// bounded softmax, fused Q-norm) + XCD-aware block swizzle (all 16 q-blocks
// of a bh land on one presumed XCD -> K/V tiles stay L2-resident).
// Prepass: single kernel = register-resident K-norm + V bf16 cast.

#define T_SEQ 2048
#define DH 128
#define BH 32   // B*H

typedef float f32x4 __attribute__((ext_vector_type(4)));
typedef __bf16 bf16x8 __attribute__((ext_vector_type(8)));
typedef __bf16 bf16x4 __attribute__((ext_vector_type(4)));

__device__ __forceinline__ void async_copy16(const void* g, void* l) {
  __builtin_amdgcn_global_load_lds(
      (const __attribute__((address_space(1))) void*)g,
      (__attribute__((address_space(3))) void*)l, 16, 0, 0);
}

// ---------- fused prepass ----------
// blocks [0,1024): K norm+transpose  ksrc [bh][128][T] f32 -> kn [bh][T][128] bf16
// blocks [1024,5120): V cast f32->bf16, layout preserved [bh][128][T]
__global__ __launch_bounds__(256) void prepass_kernel(
    const float* __restrict__ ksrc, const float* __restrict__ vsrc,
    __bf16* __restrict__ kn, __bf16* __restrict__ vb) {
  __shared__ float part[4][64];
  __shared__ float inv_s[64];
  __shared__ __bf16 tile[64 * 136];   // [t][ch] stride 136
  const int tid = threadIdx.x;

  if (blockIdx.x >= 1024) {           // ---- V cast
    int i = (blockIdx.x - 1024) * 256 + tid;
    f32x4 a = *(const f32x4*)(vsrc + (size_t)i * 8);
    f32x4 b = *(const f32x4*)(vsrc + (size_t)i * 8 + 4);
    bf16x8 ob;
    ob[0] = (__bf16)a[0]; ob[1] = (__bf16)a[1]; ob[2] = (__bf16)a[2]; ob[3] = (__bf16)a[3];
    ob[4] = (__bf16)b[0]; ob[5] = (__bf16)b[1]; ob[6] = (__bf16)b[2]; ob[7] = (__bf16)b[3];
    *(bf16x8*)(vb + (size_t)i * 8) = ob;
    return;
  }

  // ---- K norm: wave=seg -> 32-ch chunk, lane=t; register-resident
  const int bh = blockIdx.x >> 5;
  const int t0 = (blockIdx.x & 31) * 64;
  const int seg = tid >> 6;
  const int t = tid & 63;

  const float* src = ksrc + (size_t)bh * DH * T_SEQ + t0 + t;
  float x[32];
  float ss = 0.f;
#pragma unroll
  for (int i = 0; i < 32; ++i) {
    x[i] = src[(size_t)(seg * 32 + i) * T_SEQ];
    ss += x[i] * x[i];
  }
  part[seg][t] = ss;
  __syncthreads();
  if (tid < 64) {
    float n = sqrtf(part[0][tid] + part[1][tid] + part[2][tid] + part[3][tid]);
    inv_s[tid] = 1.f / fmaxf(n, 1e-12f);
  }
  __syncthreads();
  const float inv = inv_s[t];
#pragma unroll
  for (int o = 0; o < 4; ++o) {
    bf16x8 ob;
#pragma unroll
    for (int j = 0; j < 8; ++j) ob[j] = (__bf16)(x[o * 8 + j] * inv);
    *(bf16x8*)(tile + t * 136 + seg * 32 + o * 8) = ob;
  }
  __syncthreads();
  const int t2 = tid >> 2;
  const int c0 = (tid & 3) * 32;
  __bf16* drow = kn + (size_t)(bh * T_SEQ + t0 + t2) * DH + c0;
#pragma unroll
  for (int cc = 0; cc < 4; ++cc)
    *(bf16x8*)(drow + cc * 8) = *(const bf16x8*)(tile + t2 * 136 + c0 + cc * 8);
}

// ---------- flash attention (R3 structure) ----------
__device__ __forceinline__ void stage_tiles(
    const __bf16* kbase, const __bf16* vbase, __bf16* lk, __bf16* lv,
    int koff, int w, int qi, int g) {
#pragma unroll
  for (int i = 0; i < 4; ++i) {
    const int f = w * 4 + i;          // K frag: mt = f>>2, s = f&3
    const int mt = f >> 2, s = f & 3;
    async_copy16(kbase + (size_t)(koff + mt * 16 + qi) * DH + s * 32 + g * 8,
                 lk + f * 512);
  }
#pragma unroll
  for (int i = 0; i < 4; ++i) {
    const int f = w * 4 + i;          // V frag: mt = f>>1, st = f&1
    const int mt = f >> 1, st = f & 1;
    async_copy16(vbase + (size_t)(mt * 16 + qi) * T_SEQ + koff + st * 32 + g * 8,
                 lv + f * 512);
  }
}

__global__ __launch_bounds__(256, 2) void attn_kernel(
    const float* __restrict__ q, const __bf16* __restrict__ kn,
    const __bf16* __restrict__ vb, float* __restrict__ out) {
  __shared__ __align__(16) __bf16 lds_k[2][16 * 512];   // 32 KB
  __shared__ __align__(16) __bf16 lds_v[2][16 * 512];   // 32 KB
  __shared__ __align__(16) __bf16 p_buf[8 * 1024];      // 16 KB, XOR-swizzled
  // total 81920 B -> 2 blocks/CU

  // XCD-aware swizzle: presumed XCD = blockIdx&7; all 16 q-tiles of a bh on
  // one XCD (4 bh per XCD, ~4 MB bf16 K+V working set = one L2).
  const int bh = (blockIdx.x & 7) + ((blockIdx.x >> 3) & 3) * 8;
  const int q0 = (blockIdx.x >> 5) * 128;
  const int tid = threadIdx.x;
  const int w = tid >> 6, lane = tid & 63;
  const int qi = lane & 15, g = lane >> 4;

  const __bf16* kbase = kn + (size_t)bh * (T_SEQ * DH);
  const __bf16* vbase = vb + (size_t)bh * (DH * T_SEQ);
  const float* qsrc = q + (size_t)bh * (DH * T_SEQ);

  // kick iter-0 staging first; Q-norm below overlaps the DMA latency
  stage_tiles(kbase, vbase, lds_k[0], lds_v[0], 0, w, qi, g);

  // fused Q normalize (alpha folded): qf = B[n=q][k=ch] frags
  bf16x8 qf[2][4];
#pragma unroll
  for (int nt = 0; nt < 2; ++nt) {
    const int t = q0 + w * 32 + nt * 16 + qi;
    float xv[32];
    float ss = 0.f;
#pragma unroll
    for (int s = 0; s < 4; ++s)
#pragma unroll
      for (int j = 0; j < 8; ++j) {
        float xq = qsrc[(size_t)(s * 32 + g * 8 + j) * T_SEQ + t];
        xv[s * 8 + j] = xq;
        ss += xq * xq;
      }
    ss += __shfl_xor(ss, 16, 64);   // sum across the 4 g-quads (same qi)
    ss += __shfl_xor(ss, 32, 64);
    const float inv = 5.0f / fmaxf(sqrtf(ss), 1e-12f);
#pragma unroll
    for (int s = 0; s < 4; ++s) {
      bf16x8 f;
#pragma unroll
      for (int j = 0; j < 8; ++j) f[j] = (__bf16)(xv[s * 8 + j] * inv);
      qf[nt][s] = f;
    }
  }

  f32x4 o_acc[2][8];
#pragma unroll
  for (int nt = 0; nt < 2; ++nt)
#pragma unroll
    for (int i = 0; i < 8; ++i) o_acc[nt][i] = (f32x4)(0.f);
  float lsum[2] = {0.f, 0.f};

  const int swz = (qi & 7) << 3;
  __bf16* pw0 = p_buf + (w * 2 + 0) * 1024 + qi * 64;
  __bf16* pw1 = p_buf + (w * 2 + 1) * 1024 + qi * 64;

  for (int it = 0; it < 32; ++it) {
    __syncthreads();   // drains own DMA (issued a full iter ago); fences buffers
    const int cur = it & 1;
    if (it + 1 < 32)   // prefetch next tiles into the other buffer
      stage_tiles(kbase, vbase, lds_k[cur ^ 1], lds_v[cur ^ 1],
                  (it + 1) * 64, w, qi, g);

    // ---- S^T = K . Q (A-frag shared across both n-tiles) ----
    const __bf16* lk = lds_k[cur];
    f32x4 sacc[2][4];
#pragma unroll
    for (int nt = 0; nt < 2; ++nt)
#pragma unroll
      for (int mt = 0; mt < 4; ++mt) sacc[nt][mt] = (f32x4)(0.f);
#pragma unroll
    for (int s = 0; s < 4; ++s)
#pragma unroll
      for (int mt = 0; mt < 4; ++mt) {
        bf16x8 a = *(const bf16x8*)(lk + ((mt * 4 + s) * 64 + lane) * 8);
        sacc[0][mt] = __builtin_amdgcn_mfma_f32_16x16x32_bf16(a, qf[0][s], sacc[0][mt], 0, 0, 0);
        sacc[1][mt] = __builtin_amdgcn_mfma_f32_16x16x32_bf16(a, qf[1][s], sacc[1][mt], 0, 0, 0);
      }

    // ---- bounded softmax: p = exp(s), s in [-5,5]; no max tracking ----
#pragma unroll
    for (int nt = 0; nt < 2; ++nt) {
      __bf16* pw = nt ? pw1 : pw0;
      float rs = 0.f;
#pragma unroll
      for (int mt = 0; mt < 4; ++mt) {
        bf16x4 pb;
#pragma unroll
        for (int r = 0; r < 4; ++r) {
          float e = __expf(sacc[nt][mt][r]);
          rs += e;
          pb[r] = (__bf16)e;
        }
        *(bf16x4*)(pw + ((mt * 16 + g * 4) ^ swz)) = pb;
      }
      lsum[nt] += rs;
    }

    // ---- O^T += V . P^T (V A-frag shared across both n-tiles) ----
    const __bf16* lv = lds_v[cur];
#pragma unroll
    for (int st = 0; st < 2; ++st) {
      bf16x8 pf0 = *(const bf16x8*)(pw0 + ((st * 32 + g * 8) ^ swz));
      bf16x8 pf1 = *(const bf16x8*)(pw1 + ((st * 32 + g * 8) ^ swz));
#pragma unroll
      for (int mt = 0; mt < 8; ++mt) {
        bf16x8 a = *(const bf16x8*)(lv + ((mt * 2 + st) * 64 + lane) * 8);
        o_acc[0][mt] = __builtin_amdgcn_mfma_f32_16x16x32_bf16(a, pf0, o_acc[0][mt], 0, 0, 0);
        o_acc[1][mt] = __builtin_amdgcn_mfma_f32_16x16x32_bf16(a, pf1, o_acc[1][mt], 0, 0, 0);
      }
    }
  }

  // ---- epilogue: reduce l across quads; C row=ch=mt*16+g*4+r, col=q ----
#pragma unroll
  for (int nt = 0; nt < 2; ++nt) {
    float l = lsum[nt];
    l += __shfl_xor(l, 16, 64);
    l += __shfl_xor(l, 32, 64);
    const float rinv = 1.f / l;
    const int tq = q0 + w * 32 + nt * 16 + qi;
#pragma unroll
    for (int mt = 0; mt < 8; ++mt)
#pragma unroll
      for (int r = 0; r < 4; ++r)
        out[(size_t)(bh * DH + mt * 16 + g * 4 + r) * T_SEQ + tq] =
            o_acc[nt][mt][r] * rinv;
  }
}

extern "C" void kernel_launch(void* const* d_in, const int* in_sizes, int n_in,
                              void* d_out, int out_size, void* d_ws, size_t ws_size,
                              hipStream_t stream) {
  const float* q = (const float*)d_in[0];
  const float* k = (const float*)d_in[1];
  const float* v = (const float*)d_in[2];
  float* out = (float*)d_out;
  const size_t n = (size_t)BH * T_SEQ * DH;
  if (ws_size < 2 * n * sizeof(__bf16)) return;
  __bf16* kn = (__bf16*)d_ws;
  __bf16* vbf = kn + n;

  prepass_kernel<<<dim3(1024 + 4096), dim3(256), 0, stream>>>(k, v, kn, vbf);
  attn_kernel<<<dim3(512), dim3(256), 0, stream>>>(q, kn, vbf, out);
}